// Round 5
// baseline (143.030 us; speedup 1.0000x reference)
//
#include <hip/hip_runtime.h>
#include <math.h>

// GAT layer. B=16, N=1024, IN=128, H=2, D=64.
// out = elu( softmax_m(leakyrelu(e_src[n]+e_dst[m])) @ hp + h )
//
// R10: SINGLE persistent kernel (512 blocks x 256 thr, exactly 2 blocks/CU)
//   replacing prep+hp+att. Rationale: measured kernel-side time ~42us vs
//   ~12-16us pipe-work model; the residual is dispatch serialization (3
//   graph-serialized launches). Noise floor is +-2-3us (fill jitter), so only
//   structural >=5us changes are benchable.
//   - phase 0: every block packs W (64KB fp32, L2-hot) -> LDS bf16 k-major-8
//     (same layout as old Wp). No prep dispatch; MFMA loop still reads b128
//     fragments (from LDS) -- NOT R6's per-MFMA scalar-load scheme.
//   - phase 1: hp = h @ Wcat -> hpB k-packed bf16 + es/ed/E1/E5 fused
//     (R8 exp2-precompute kept: no trans ops in att main loop).
//   - grid barrier: block-0-sentinel init (poison-proof: magic != repeated
//     bytes), agent-scope atomics for cross-XCD visibility; residency is
//     resource-guaranteed (LDS 35.8KB, VGPR<=256 via (256,2)) => no deadlock.
//   - phase 2: att, 2 units/block sharing bh (hb slice L2-hot, dmax hoisted);
//     LDS red overlays the W-pack buffer.
// dur_us carries ~42-44us fixed harness reset traffic (256 MiB ws re-poison).

#define LOG2E 1.44269504088896340736f
#define MAGIC_READY 0x1F2E3D4Cu
#define MAGIC_GO    0x600DF00Du

typedef __bf16 bf16x8 __attribute__((ext_vector_type(8)));
typedef float floatx4 __attribute__((ext_vector_type(4)));

union U16x8 { uint4 u; bf16x8 b; };

__device__ __forceinline__ unsigned short f2bf(float f) {
    union { __bf16 b; unsigned short u; } x;
    x.b = (__bf16)f;
    return x.u;
}

__global__ __launch_bounds__(256, 2) void gat_fused(
    const float* __restrict__ hg,        // (16384,128)
    const float* __restrict__ Wg,        // (2,128,64) fp32
    const float* __restrict__ ag,        // (2,128) fp32
    unsigned short* __restrict__ hpB,    // (32,128,64,8) bf16
    float* __restrict__ es_g,            // (32,1024)
    float* __restrict__ ed_g,            // (32,1024)
    float* __restrict__ e1_g,            // (32,1024) = 2^(ed*LOG2E)
    float* __restrict__ e5_g,            // (32,1024) = 2^(ed*0.2*LOG2E)
    float* __restrict__ out,
    unsigned* __restrict__ gsync)        // [cnt, flag]
{
    __shared__ float smem[4 * 64 * 35];  // 35.8 KB; ph0/1: W pack (32 KB); ph2: red

    const int t = threadIdx.x;
    const int lane = t & 63;
    const int w = t >> 6;
    const int col = lane & 15, quad = lane >> 4;

    // sentinel init: all 512 blocks are resident from t0 (exact-capacity grid),
    // so this completes long before any block reaches the barrier.
    if (blockIdx.x == 0 && t == 0) {
        __hip_atomic_store(&gsync[0], 0u, __ATOMIC_RELAXED, __HIP_MEMORY_SCOPE_AGENT);
        __hip_atomic_store(&gsync[1], MAGIC_READY, __ATOMIC_RELEASE, __HIP_MEMORY_SCOPE_AGENT);
    }

    // ---- phase 0: W -> LDS bf16 k-major-8 (every block; W is L2-hot) ----
    {
        unsigned short* Wlds = (unsigned short*)smem;
#pragma unroll 4
        for (int i = 0; i < 64; ++i) {
            int idx = i * 256 + t;                  // 16384 total
            int c = idx & 127, k = idx >> 7;
            float v = Wg[(c >> 6) * 8192 + k * 64 + (c & 63)];
            Wlds[((k >> 3) * 128 + c) * 8 + (k & 7)] = f2bf(v);
        }
    }
    __syncthreads();

    // ---- phase 1: hp = h @ Wcat; wave = (16-row tile, head) ----
    {
        const int wv = blockIdx.x * 4 + w;          // 0..2047
        const int rt = wv >> 1;
        const int half = wv & 1;
        const int n0 = rt * 16;

        floatx4 acc[4];
#pragma unroll
        for (int ct = 0; ct < 4; ++ct) acc[ct] = (floatx4){0.f, 0.f, 0.f, 0.f};

        const float* hrow = hg + (size_t)(n0 + col) * 128;
        const uint4* wl4 = (const uint4*)smem;
#pragma unroll
        for (int kq = 0; kq < 4; ++kq) {
            float4 h0 = *(const float4*)(hrow + kq * 32 + quad * 8);
            float4 h1 = *(const float4*)(hrow + kq * 32 + quad * 8 + 4);
            bf16x8 af;
            af[0] = (__bf16)h0.x; af[1] = (__bf16)h0.y;
            af[2] = (__bf16)h0.z; af[3] = (__bf16)h0.w;
            af[4] = (__bf16)h1.x; af[5] = (__bf16)h1.y;
            af[6] = (__bf16)h1.z; af[7] = (__bf16)h1.w;
            const uint4* wbase = wl4 + (kq * 4 + quad) * 128 + half * 64;
#pragma unroll
            for (int ct = 0; ct < 4; ++ct) {
                U16x8 bu; bu.u = wbase[ct * 16 + col];
                acc[ct] = __builtin_amdgcn_mfma_f32_16x16x32_bf16(af, bu.b, acc[ct], 0, 0, 0);
            }
        }

        const int b = n0 >> 10;
        const int nloc = n0 & 1023;
        const int bh = b * 2 + half;

        // fused e_src / e_dst; a read direct from ag (acat[c] == ag[half*128+dd],
        // acat[128+c] == ag[half*128+64+dd], dd = ct*16+col)
        float esr[4] = {0.f, 0.f, 0.f, 0.f}, edr[4] = {0.f, 0.f, 0.f, 0.f};
#pragma unroll
        for (int ct = 0; ct < 4; ++ct) {
            int dd = ct * 16 + col;
            float as = ag[half * 128 + dd];
            float ad = ag[half * 128 + 64 + dd];
#pragma unroll
            for (int r = 0; r < 4; ++r) {
                esr[r] = fmaf(acc[ct][r], as, esr[r]);
                edr[r] = fmaf(acc[ct][r], ad, edr[r]);
            }
        }
#pragma unroll
        for (int off = 1; off <= 8; off <<= 1) {
#pragma unroll
            for (int r = 0; r < 4; ++r) {
                esr[r] += __shfl_xor(esr[r], off, 64);
                edr[r] += __shfl_xor(edr[r], off, 64);
            }
        }
        if (col == 0) {
            size_t base = (size_t)bh * 1024 + nloc + quad * 4;
#pragma unroll
            for (int r = 0; r < 4; ++r) {
                es_g[base + r] = esr[r];
                ed_g[base + r] = edr[r];
                e1_g[base + r] = __builtin_amdgcn_exp2f(edr[r] * LOG2E);
                e5_g[base + r] = __builtin_amdgcn_exp2f(edr[r] * (0.2f * LOG2E));
            }
        }

        // hpB stores: rows n = n0 + quad*4 + r; n%8 = (quad&1)*4 + r
        const int gloc = (nloc >> 3) + (quad >> 1);
#pragma unroll
        for (int ct = 0; ct < 4; ++ct) {
            int d = ct * 16 + col;
            uint2 pk;
            pk.x = (unsigned)f2bf(acc[ct][0]) | ((unsigned)f2bf(acc[ct][1]) << 16);
            pk.y = (unsigned)f2bf(acc[ct][2]) | ((unsigned)f2bf(acc[ct][3]) << 16);
            size_t idx = ((size_t)(bh * 128 + gloc) * 64 + d) * 8 + (quad & 1) * 4;
            *(uint2*)(hpB + idx) = pk;
        }
    }

    // ---- grid barrier (agent scope: cross-XCD visibility) ----
    __syncthreads();                      // block's stores drained to L2
    if (t == 0) {
        __threadfence();                  // XCD L2 -> device-visible
        while (__hip_atomic_load(&gsync[1], __ATOMIC_ACQUIRE, __HIP_MEMORY_SCOPE_AGENT) != MAGIC_READY) {}
        unsigned v = __hip_atomic_fetch_add(&gsync[0], 1u, __ATOMIC_ACQ_REL, __HIP_MEMORY_SCOPE_AGENT);
        if (v == 511u) {
            __hip_atomic_store(&gsync[1], MAGIC_GO, __ATOMIC_RELEASE, __HIP_MEMORY_SCOPE_AGENT);
        } else {
            while (__hip_atomic_load(&gsync[1], __ATOMIC_ACQUIRE, __HIP_MEMORY_SCOPE_AGENT) != MAGIC_GO)
                __builtin_amdgcn_s_sleep(2);
        }
    }
    __syncthreads();                      // acquire (t0's inv) ordered before reads

    // ---- phase 2: attention, 2 units per block, shared bh ----
    {
        const int bh = blockIdx.x & 31;
        const int nt0 = blockIdx.x >> 5;   // 0..15; units: nt0, nt0+16
        const int b = bh >> 1, hh = bh & 1;

        const float* edrow = ed_g + (size_t)bh * 1024;
        const float* e1row = e1_g + (size_t)bh * 1024;
        const float* e5row = e5_g + (size_t)bh * 1024;
        const uint4* hb = (const uint4*)hpB + (size_t)bh * 8192;
        const int mbase = w * 256;         // 4-way split-m
        float* red = smem;                 // [wave][lane][2x16 acc + 2 lsum], stride 35

        // dmax over full row (shared by both units)
        float mx = -1e30f;
#pragma unroll
        for (int i = 0; i < 4; ++i) {
            float4 v = *(const float4*)(edrow + lane * 16 + i * 4);
            mx = fmaxf(mx, fmaxf(fmaxf(v.x, v.y), fmaxf(v.z, v.w)));
        }
#pragma unroll
        for (int off = 1; off < 64; off <<= 1) mx = fmaxf(mx, __shfl_xor(mx, off, 64));
        const float mxl = mx * LOG2E;

#pragma unroll 1
        for (int u = 0; u < 2; ++u) {
            const int n0 = (nt0 + u * 16) * 32;
            __syncthreads();               // red reuse guard between units

            // closed-form row max per 16-row subtile (log2 domain);
            // P = max(E1[m]*C2, E5[m]*C5): no exp2 in main loop.
            const float s2a = es_g[(size_t)bh * 1024 + n0 + col] * LOG2E;
            const float s2b = es_g[(size_t)bh * 1024 + n0 + 16 + col] * LOG2E;
            const float x0a = s2a + mxl, x0b = s2b + mxl;
            const float Ma = fmaxf(x0a, 0.2f * x0a), Mb = fmaxf(x0b, 0.2f * x0b);
            const float C2a = __builtin_amdgcn_exp2f(s2a - Ma);
            const float C5a = __builtin_amdgcn_exp2f(0.2f * s2a - Ma);
            const float C2b = __builtin_amdgcn_exp2f(s2b - Mb);
            const float C5b = __builtin_amdgcn_exp2f(0.2f * s2b - Mb);

            floatx4 acc0[4], acc1[4];
#pragma unroll
            for (int ct = 0; ct < 4; ++ct) {
                acc0[ct] = (floatx4){0.f, 0.f, 0.f, 0.f};
                acc1[ct] = (floatx4){0.f, 0.f, 0.f, 0.f};
            }
            float ls0 = 0.f, ls1 = 0.f;

            // register double-buffer: preload chunk 0
            float4 d0 = *(const float4*)(e1row + mbase + quad * 8);
            float4 d1 = *(const float4*)(e1row + mbase + quad * 8 + 4);
            float4 f0 = *(const float4*)(e5row + mbase + quad * 8);
            float4 f1 = *(const float4*)(e5row + mbase + quad * 8 + 4);
            int gm = (mbase >> 3) + quad;
            uint4 bu0 = hb[gm * 64 + col];
            uint4 bu1 = hb[gm * 64 + 16 + col];
            uint4 bu2 = hb[gm * 64 + 32 + col];
            uint4 bu3 = hb[gm * 64 + 48 + col];

#pragma unroll
            for (int i = 0; i < 8; ++i) {
                float4 c0 = d0, c1 = d1, g0 = f0, g1 = f1;
                uint4 cb0 = bu0, cb1 = bu1, cb2 = bu2, cb3 = bu3;
                if (i < 7) {
                    int m1 = mbase + (i + 1) * 32;
                    d0 = *(const float4*)(e1row + m1 + quad * 8);
                    d1 = *(const float4*)(e1row + m1 + quad * 8 + 4);
                    f0 = *(const float4*)(e5row + m1 + quad * 8);
                    f1 = *(const float4*)(e5row + m1 + quad * 8 + 4);
                    gm = (m1 >> 3) + quad;
                    bu0 = hb[gm * 64 + col];
                    bu1 = hb[gm * 64 + 16 + col];
                    bu2 = hb[gm * 64 + 32 + col];
                    bu3 = hb[gm * 64 + 48 + col];
                }
                float ev[8] = {c0.x, c0.y, c0.z, c0.w, c1.x, c1.y, c1.z, c1.w};
                float fv[8] = {g0.x, g0.y, g0.z, g0.w, g1.x, g1.y, g1.z, g1.w};
                bf16x8 af0, af1;
#pragma unroll
                for (int j = 0; j < 8; ++j) {
                    float pa = fmaxf(ev[j] * C2a, fv[j] * C5a);
                    float pb = fmaxf(ev[j] * C2b, fv[j] * C5b);
                    ls0 += pa; ls1 += pb;
                    af0[j] = (__bf16)pa;
                    af1[j] = (__bf16)pb;
                }
                U16x8 u0; u0.u = cb0;
                U16x8 u1; u1.u = cb1;
                U16x8 u2; u2.u = cb2;
                U16x8 u3; u3.u = cb3;
                acc0[0] = __builtin_amdgcn_mfma_f32_16x16x32_bf16(af0, u0.b, acc0[0], 0, 0, 0);
                acc1[0] = __builtin_amdgcn_mfma_f32_16x16x32_bf16(af1, u0.b, acc1[0], 0, 0, 0);
                acc0[1] = __builtin_amdgcn_mfma_f32_16x16x32_bf16(af0, u1.b, acc0[1], 0, 0, 0);
                acc1[1] = __builtin_amdgcn_mfma_f32_16x16x32_bf16(af1, u1.b, acc1[1], 0, 0, 0);
                acc0[2] = __builtin_amdgcn_mfma_f32_16x16x32_bf16(af0, u2.b, acc0[2], 0, 0, 0);
                acc1[2] = __builtin_amdgcn_mfma_f32_16x16x32_bf16(af1, u2.b, acc1[2], 0, 0, 0);
                acc0[3] = __builtin_amdgcn_mfma_f32_16x16x32_bf16(af0, u3.b, acc0[3], 0, 0, 0);
                acc1[3] = __builtin_amdgcn_mfma_f32_16x16x32_bf16(af1, u3.b, acc1[3], 0, 0, 0);
            }

            // per-wave row-sums over this m-range
            ls0 += __shfl_xor(ls0, 16, 64); ls0 += __shfl_xor(ls0, 32, 64);
            ls1 += __shfl_xor(ls1, 16, 64); ls1 += __shfl_xor(ls1, 32, 64);

            // write partials (stride 35: conflict-free scalar access)
            float* myred = red + (w * 64 + lane) * 35;
#pragma unroll
            for (int ct = 0; ct < 4; ++ct)
#pragma unroll
                for (int r = 0; r < 4; ++r) {
                    myred[ct * 4 + r]      = acc0[ct][r];
                    myred[16 + ct * 4 + r] = acc1[ct][r];
                }
            myred[32] = ls0;
            myred[33] = ls1;
            __syncthreads();

            // combine: wave owns (subtile = w&1, ct pair = w>>1)
            const int tile = w & 1;
            const int ctp = w >> 1;
            float ltot = 0.f;
#pragma unroll
            for (int v4 = 0; v4 < 4; ++v4)
                ltot += red[(v4 * 64 + lane) * 35 + 32 + tile];
            float inv[4];
#pragma unroll
            for (int r = 0; r < 4; ++r)
                inv[r] = __builtin_amdgcn_rcpf(__shfl(ltot, quad * 4 + r, 16));

#pragma unroll
            for (int cti = 0; cti < 2; ++cti) {
                const int ct = ctp * 2 + cti;
                float facc[4] = {0.f, 0.f, 0.f, 0.f};
#pragma unroll
                for (int v4 = 0; v4 < 4; ++v4) {
                    const float* rr = red + (v4 * 64 + lane) * 35 + tile * 16 + ct * 4;
#pragma unroll
                    for (int r = 0; r < 4; ++r) facc[r] += rr[r];
                }
#pragma unroll
                for (int r = 0; r < 4; ++r) {
                    int n = n0 + tile * 16 + quad * 4 + r;
                    size_t off = (size_t)(b * 1024 + n) * 128 + hh * 64 + ct * 16 + col;
                    float vv = facc[r] * inv[r] + hg[off];
                    out[off] = vv > 0.f ? vv : __builtin_amdgcn_exp2f(vv * LOG2E) - 1.f;
                }
            }
        }
    }
}

// ---------------------------------------------------------------------------
extern "C" void kernel_launch(void* const* d_in, const int* in_sizes, int n_in,
                              void* d_out, int out_size, void* d_ws, size_t ws_size,
                              hipStream_t stream) {
    const float* h = (const float*)d_in[0];   // (16,1024,128)
    const float* W = (const float*)d_in[1];   // (2,128,64)
    const float* a = (const float*)d_in[2];   // (2,128,1)
    float* out = (float*)d_out;

    unsigned short* hpB = (unsigned short*)d_ws;                    // 4 MB
    float* es  = (float*)((char*)d_ws + (4u << 20));                // 128 KB
    float* ed  = es + 32 * 1024;                                    // 128 KB
    float* e1  = ed + 32 * 1024;                                    // 128 KB
    float* e5  = e1 + 32 * 1024;                                    // 128 KB
    unsigned* gsync = (unsigned*)(e5 + 32 * 1024);                  // 8 B

    gat_fused<<<512, 256, 0, stream>>>(h, W, a, hpB, es, ed, e1, e5, out, gsync);
}

// Round 6
// 83.206 us; speedup vs baseline: 1.7190x; 1.7190x over previous
//
#include <hip/hip_runtime.h>
#include <math.h>

// GAT layer. B=16, N=1024, IN=128, H=2, D=64.
// out = elu( softmax_m(leakyrelu(e_src[n]+e_dst[m])) @ hp + h )
//
// R11: R9 structure, prep MERGED into hp (no grid barrier needed for it):
//   every hp block packs W (64KB fp32, L2-hot) into its OWN LDS (32KB) --
//   R10's phase0+1, correctness-verified in R10. hp->att stays a dispatch
//   boundary: att consumes all blocks' hpB, and R10 PROVED the HW boundary
//   is the cheap grid barrier -- software agent-scope barrier cost +57us
//   (512 serialized cross-XCD RMWs + 512 per-block threadfence L2 writebacks;
//   fused kernel alone 87-95us, MfmaUtil 2%). NEVER re-attempt spin barriers
//   after an MB-scale-dirty-L2 producer phase.
//   Boundary-gap model from R10: ~5-7us per dispatch boundary in this
//   graph-captured harness => 4->3 dispatches should save ~6-8us.
// gat_hp (512 blocks): LDS W-pack + hp = h @ Wcat via mfma_16x16x32_bf16
//   -> hpB k-packed bf16 + es/ed/E1/E5 fused (R8 exp2-precompute kept).
// gat_att (1024 blocks): R9 VERBATIM. block = (bh, 32-row n-tile); 4 waves
//   split m 4-way, register double-buffer; P = max(E1[m]*C2, E5[m]*C5) --
//   no trans ops in main loop. __launch_bounds__(256,2).
// dur_us carries ~42-44us fixed harness reset traffic (256 MiB ws re-poison);
//   noise floor +-2-3us.

#define LOG2E 1.44269504088896340736f

typedef __bf16 bf16x8 __attribute__((ext_vector_type(8)));
typedef float floatx4 __attribute__((ext_vector_type(4)));

union U16x8 { uint4 u; bf16x8 b; };

__device__ __forceinline__ unsigned short f2bf(float f) {
    union { __bf16 b; unsigned short u; } x;
    x.b = (__bf16)f;
    return x.u;
}

// ---------------------------------------------------------------------------
// Kernel A: per-block LDS W-pack, then hp = h @ Wcat. 512 blocks x 256 thr;
// wave = (16-row tile, head).
// ---------------------------------------------------------------------------
__global__ __launch_bounds__(256) void gat_hp(
    const float* __restrict__ hg,        // (16384,128)
    const float* __restrict__ Wg,        // (2,128,64) fp32
    const float* __restrict__ ag,        // (2,128) fp32
    unsigned short* __restrict__ hpB,    // (32,128,64,8) bf16
    float* __restrict__ es_g,            // (32,1024)
    float* __restrict__ ed_g,            // (32,1024)
    float* __restrict__ e1_g,            // (32,1024) = 2^(ed*LOG2E)
    float* __restrict__ e5_g)            // (32,1024) = 2^(ed*0.2*LOG2E)
{
    __shared__ unsigned short Wlds[16384];   // 32 KB: bf16 k-major-8 W pack

    const int t = threadIdx.x;
    const int lane = t & 63;
    const int w = t >> 6;
    const int col = lane & 15, quad = lane >> 4;

    // ---- W -> LDS bf16 k-major-8 (every block; W is L2-hot) ----
#pragma unroll 4
    for (int i = 0; i < 64; ++i) {
        int idx = i * 256 + t;                  // 16384 total
        int c = idx & 127, k = idx >> 7;
        float v = Wg[(c >> 6) * 8192 + k * 64 + (c & 63)];
        Wlds[((k >> 3) * 128 + c) * 8 + (k & 7)] = f2bf(v);
    }
    __syncthreads();

    const int wv = blockIdx.x * 4 + w;          // 0..2047
    const int rt = wv >> 1;                     // global 16-row tile, 0..1023
    const int half = wv & 1;                    // head
    const int n0 = rt * 16;

    floatx4 acc[4];
#pragma unroll
    for (int ct = 0; ct < 4; ++ct) acc[ct] = (floatx4){0.f, 0.f, 0.f, 0.f};

    const float* hrow = hg + (size_t)(n0 + col) * 128;
    const uint4* wl4 = (const uint4*)Wlds;
#pragma unroll
    for (int kq = 0; kq < 4; ++kq) {
        float4 h0 = *(const float4*)(hrow + kq * 32 + quad * 8);
        float4 h1 = *(const float4*)(hrow + kq * 32 + quad * 8 + 4);
        bf16x8 af;
        af[0] = (__bf16)h0.x; af[1] = (__bf16)h0.y;
        af[2] = (__bf16)h0.z; af[3] = (__bf16)h0.w;
        af[4] = (__bf16)h1.x; af[5] = (__bf16)h1.y;
        af[6] = (__bf16)h1.z; af[7] = (__bf16)h1.w;
        const uint4* wbase = wl4 + (kq * 4 + quad) * 128 + half * 64;
#pragma unroll
        for (int ct = 0; ct < 4; ++ct) {
            U16x8 bu; bu.u = wbase[ct * 16 + col];
            acc[ct] = __builtin_amdgcn_mfma_f32_16x16x32_bf16(af, bu.b, acc[ct], 0, 0, 0);
        }
    }

    const int b = n0 >> 10;
    const int nloc = n0 & 1023;
    const int bh = b * 2 + half;

    // fused e_src / e_dst from fp32 accumulators; a read direct from ag
    float esr[4] = {0.f, 0.f, 0.f, 0.f}, edr[4] = {0.f, 0.f, 0.f, 0.f};
#pragma unroll
    for (int ct = 0; ct < 4; ++ct) {
        int dd = ct * 16 + col;
        float as = ag[half * 128 + dd];
        float ad = ag[half * 128 + 64 + dd];
#pragma unroll
        for (int r = 0; r < 4; ++r) {
            esr[r] = fmaf(acc[ct][r], as, esr[r]);
            edr[r] = fmaf(acc[ct][r], ad, edr[r]);
        }
    }
#pragma unroll
    for (int off = 1; off <= 8; off <<= 1) {
#pragma unroll
        for (int r = 0; r < 4; ++r) {
            esr[r] += __shfl_xor(esr[r], off, 64);
            edr[r] += __shfl_xor(edr[r], off, 64);
        }
    }
    if (col == 0) {
        size_t base = (size_t)bh * 1024 + nloc + quad * 4;
#pragma unroll
        for (int r = 0; r < 4; ++r) {
            es_g[base + r] = esr[r];
            ed_g[base + r] = edr[r];
            e1_g[base + r] = __builtin_amdgcn_exp2f(edr[r] * LOG2E);
            e5_g[base + r] = __builtin_amdgcn_exp2f(edr[r] * (0.2f * LOG2E));
        }
    }

    // hpB stores: rows n = n0 + quad*4 + r; n%8 = (quad&1)*4 + r
    const int gloc = (nloc >> 3) + (quad >> 1);
#pragma unroll
    for (int ct = 0; ct < 4; ++ct) {
        int d = ct * 16 + col;
        uint2 pk;
        pk.x = (unsigned)f2bf(acc[ct][0]) | ((unsigned)f2bf(acc[ct][1]) << 16);
        pk.y = (unsigned)f2bf(acc[ct][2]) | ((unsigned)f2bf(acc[ct][3]) << 16);
        size_t idx = ((size_t)(bh * 128 + gloc) * 64 + d) * 8 + (quad & 1) * 4;
        *(uint2*)(hpB + idx) = pk;
    }
}

// ---------------------------------------------------------------------------
// Kernel 2: attention. 1024 blocks x 256 thr. R9 VERBATIM.
// block = (bh = blk&31, nt = blk>>5 -> 32-row tile); 4 waves split m 4-way.
// ---------------------------------------------------------------------------
__global__ __launch_bounds__(256, 2) void gat_att(
    const float* __restrict__ hg,
    const unsigned short* __restrict__ hpB,
    const float* __restrict__ es_g,
    const float* __restrict__ ed_g,
    const float* __restrict__ e1_g,
    const float* __restrict__ e5_g,
    float* __restrict__ out)
{
    __shared__ float red[4 * 64 * 35];   // 35.8 KB: [wave][lane][2x16 acc + 2 lsum]

    const int t = threadIdx.x;
    const int lane = t & 63;
    const int w = t >> 6;
    const int bh = blockIdx.x & 31;      // same-bh blocks -> same XCD
    const int nt = blockIdx.x >> 5;      // 0..31
    const int b = bh >> 1, hh = bh & 1;
    const int n0 = nt * 32;
    const int col = lane & 15, quad = lane >> 4;

    const float* edrow = ed_g + (size_t)bh * 1024;
    const float* e1row = e1_g + (size_t)bh * 1024;
    const float* e5row = e5_g + (size_t)bh * 1024;

    // dmax over full row (per-wave, no barrier)
    float mx = -1e30f;
#pragma unroll
    for (int i = 0; i < 4; ++i) {
        float4 v = *(const float4*)(edrow + lane * 16 + i * 4);
        mx = fmaxf(mx, fmaxf(fmaxf(v.x, v.y), fmaxf(v.z, v.w)));
    }
#pragma unroll
    for (int off = 1; off < 64; off <<= 1) mx = fmaxf(mx, __shfl_xor(mx, off, 64));
    const float mxl = mx * LOG2E;

    // two 16-row subtiles; closed-form row max per subtile (log2 domain).
    // P = 2^(max(x,.2x)-M) = max(E1[m]*C2, E5[m]*C5): no exp2 in main loop.
    const float s2a = es_g[(size_t)bh * 1024 + n0 + col] * LOG2E;
    const float s2b = es_g[(size_t)bh * 1024 + n0 + 16 + col] * LOG2E;
    const float x0a = s2a + mxl, x0b = s2b + mxl;
    const float Ma = fmaxf(x0a, 0.2f * x0a), Mb = fmaxf(x0b, 0.2f * x0b);
    const float C2a = __builtin_amdgcn_exp2f(s2a - Ma);
    const float C5a = __builtin_amdgcn_exp2f(0.2f * s2a - Ma);
    const float C2b = __builtin_amdgcn_exp2f(s2b - Mb);
    const float C5b = __builtin_amdgcn_exp2f(0.2f * s2b - Mb);

    floatx4 acc0[4], acc1[4];
#pragma unroll
    for (int ct = 0; ct < 4; ++ct) {
        acc0[ct] = (floatx4){0.f, 0.f, 0.f, 0.f};
        acc1[ct] = (floatx4){0.f, 0.f, 0.f, 0.f};
    }
    float ls0 = 0.f, ls1 = 0.f;

    const uint4* hb = (const uint4*)hpB + (size_t)bh * 8192;
    const int mbase = w * 256;            // 4-way split-m

    // register double-buffer: preload chunk 0 (E1 + E5 streams)
    float4 d0 = *(const float4*)(e1row + mbase + quad * 8);
    float4 d1 = *(const float4*)(e1row + mbase + quad * 8 + 4);
    float4 f0 = *(const float4*)(e5row + mbase + quad * 8);
    float4 f1 = *(const float4*)(e5row + mbase + quad * 8 + 4);
    int gm = (mbase >> 3) + quad;
    uint4 bu0 = hb[gm * 64 + col];
    uint4 bu1 = hb[gm * 64 + 16 + col];
    uint4 bu2 = hb[gm * 64 + 32 + col];
    uint4 bu3 = hb[gm * 64 + 48 + col];

#pragma unroll
    for (int i = 0; i < 8; ++i) {
        float4 c0 = d0, c1 = d1, g0 = f0, g1 = f1;
        uint4 cb0 = bu0, cb1 = bu1, cb2 = bu2, cb3 = bu3;
        if (i < 7) {
            int m1 = mbase + (i + 1) * 32;
            d0 = *(const float4*)(e1row + m1 + quad * 8);
            d1 = *(const float4*)(e1row + m1 + quad * 8 + 4);
            f0 = *(const float4*)(e5row + m1 + quad * 8);
            f1 = *(const float4*)(e5row + m1 + quad * 8 + 4);
            gm = (m1 >> 3) + quad;
            bu0 = hb[gm * 64 + col];
            bu1 = hb[gm * 64 + 16 + col];
            bu2 = hb[gm * 64 + 32 + col];
            bu3 = hb[gm * 64 + 48 + col];
        }
        float ev[8] = {c0.x, c0.y, c0.z, c0.w, c1.x, c1.y, c1.z, c1.w};
        float fv[8] = {g0.x, g0.y, g0.z, g0.w, g1.x, g1.y, g1.z, g1.w};
        bf16x8 af0, af1;
#pragma unroll
        for (int j = 0; j < 8; ++j) {
            float pa = fmaxf(ev[j] * C2a, fv[j] * C5a);
            float pb = fmaxf(ev[j] * C2b, fv[j] * C5b);
            ls0 += pa; ls1 += pb;
            af0[j] = (__bf16)pa;
            af1[j] = (__bf16)pb;
        }
        U16x8 u0; u0.u = cb0;
        U16x8 u1; u1.u = cb1;
        U16x8 u2; u2.u = cb2;
        U16x8 u3; u3.u = cb3;
        acc0[0] = __builtin_amdgcn_mfma_f32_16x16x32_bf16(af0, u0.b, acc0[0], 0, 0, 0);
        acc1[0] = __builtin_amdgcn_mfma_f32_16x16x32_bf16(af1, u0.b, acc1[0], 0, 0, 0);
        acc0[1] = __builtin_amdgcn_mfma_f32_16x16x32_bf16(af0, u1.b, acc0[1], 0, 0, 0);
        acc1[1] = __builtin_amdgcn_mfma_f32_16x16x32_bf16(af1, u1.b, acc1[1], 0, 0, 0);
        acc0[2] = __builtin_amdgcn_mfma_f32_16x16x32_bf16(af0, u2.b, acc0[2], 0, 0, 0);
        acc1[2] = __builtin_amdgcn_mfma_f32_16x16x32_bf16(af1, u2.b, acc1[2], 0, 0, 0);
        acc0[3] = __builtin_amdgcn_mfma_f32_16x16x32_bf16(af0, u3.b, acc0[3], 0, 0, 0);
        acc1[3] = __builtin_amdgcn_mfma_f32_16x16x32_bf16(af1, u3.b, acc1[3], 0, 0, 0);
    }

    // per-wave row-sums over this m-range
    ls0 += __shfl_xor(ls0, 16, 64); ls0 += __shfl_xor(ls0, 32, 64);
    ls1 += __shfl_xor(ls1, 16, 64); ls1 += __shfl_xor(ls1, 32, 64);

    // write partials (stride 35: conflict-free scalar access)
    float* myred = red + (w * 64 + lane) * 35;
#pragma unroll
    for (int ct = 0; ct < 4; ++ct)
#pragma unroll
        for (int r = 0; r < 4; ++r) {
            myred[ct * 4 + r]      = acc0[ct][r];
            myred[16 + ct * 4 + r] = acc1[ct][r];
        }
    myred[32] = ls0;
    myred[33] = ls1;
    __syncthreads();

    // combine: wave owns (subtile = w&1, ct pair = w>>1)
    const int tile = w & 1;
    const int ctp = w >> 1;
    float ltot = 0.f;
#pragma unroll
    for (int v4 = 0; v4 < 4; ++v4)
        ltot += red[(v4 * 64 + lane) * 35 + 32 + tile];
    float inv[4];
#pragma unroll
    for (int r = 0; r < 4; ++r)
        inv[r] = __builtin_amdgcn_rcpf(__shfl(ltot, quad * 4 + r, 16));

#pragma unroll
    for (int cti = 0; cti < 2; ++cti) {
        const int ct = ctp * 2 + cti;
        float facc[4] = {0.f, 0.f, 0.f, 0.f};
#pragma unroll
        for (int v4 = 0; v4 < 4; ++v4) {
            const float* rr = red + (v4 * 64 + lane) * 35 + tile * 16 + ct * 4;
#pragma unroll
            for (int r = 0; r < 4; ++r) facc[r] += rr[r];
        }
#pragma unroll
        for (int r = 0; r < 4; ++r) {
            int n = n0 + tile * 16 + quad * 4 + r;
            size_t off = (size_t)(b * 1024 + n) * 128 + hh * 64 + ct * 16 + col;
            float vv = facc[r] * inv[r] + hg[off];
            out[off] = vv > 0.f ? vv : __builtin_amdgcn_exp2f(vv * LOG2E) - 1.f;
        }
    }
}

// ---------------------------------------------------------------------------
extern "C" void kernel_launch(void* const* d_in, const int* in_sizes, int n_in,
                              void* d_out, int out_size, void* d_ws, size_t ws_size,
                              hipStream_t stream) {
    const float* h = (const float*)d_in[0];   // (16,1024,128)
    const float* W = (const float*)d_in[1];   // (2,128,64)
    const float* a = (const float*)d_in[2];   // (2,128,1)
    float* out = (float*)d_out;

    unsigned short* hpB = (unsigned short*)d_ws;                    // 4 MB
    float* es  = (float*)((char*)d_ws + (4u << 20));                // 128 KB
    float* ed  = es + 32 * 1024;                                    // 128 KB
    float* e1  = ed + 32 * 1024;                                    // 128 KB
    float* e5  = e1 + 32 * 1024;                                    // 128 KB

    gat_hp<<<512, 256, 0, stream>>>(h, W, a, hpB, es, ed, e1, e5);
    gat_att<<<1024, 256, 0, stream>>>(h, hpB, es, ed, e1, e5, out);
}